// Round 1
// 878.871 us; speedup vs baseline: 1.0683x; 1.0683x over previous
//
#include <hip/hip_runtime.h>

typedef unsigned short u16;
typedef unsigned int u32;
typedef __bf16 bf16x8 __attribute__((ext_vector_type(8)));
typedef float f32x4 __attribute__((ext_vector_type(4)));

#define B_ 2
#define T_ 2048
#define C_ 2048
#define H_ 16
#define HS_ 128
#define AL_ 10
#define C3_ 6144
#define MASKV (-3.0e38f)   // finite "-inf": exp(MASKV - m) == 0
#define MFMA16(a, b, c) __builtin_amdgcn_mfma_f32_16x16x32_bf16(a, b, c, 0, 0, 0)

__device__ __forceinline__ float b2f(u16 v) {
  union { u32 u; float f; } x; x.u = ((u32)v) << 16; return x.f;
}
__device__ __forceinline__ u16 f2b(float f) {
  u32 u = __builtin_bit_cast(u32, f);
  return (u16)((u + 0x7FFFu + ((u >> 16) & 1u)) >> 16);  // RNE
}
// fp32 -> bf16 -> fp32 (match the np ref's bf16-cast of fp32 inputs)
__device__ __forceinline__ float rb(float f) { return b2f(f2b(f)); }

// ---------------------------------------------------------------------------
// GEMM: C(MxN) = A(MxK) * B(NxK)^T, fp32 accum. 128x128 tile, BK=32,
// 4 waves x 64x64 quadrant. (unchanged this round)
// ---------------------------------------------------------------------------
template <bool AF32, bool BF32, bool OUTF32>
__global__ __launch_bounds__(256) void gemm_nt(
    const void* __restrict__ Ap, const void* __restrict__ Bp,
    void* __restrict__ Cp, int N, int K, int lda)
{
  __shared__ u16 lA[128 * 32];
  __shared__ u16 lB[128 * 32];
  const int tid  = threadIdx.x;
  const int lane = tid & 63, wave = tid >> 6;
  const int quad = lane >> 4, l16 = lane & 15;
  const int bm = blockIdx.y * 128, bn = blockIdx.x * 128;
  const int wm = (wave >> 1) * 64, wn = (wave & 1) * 64;
  const int srow = tid >> 1, scol = (tid & 1) * 16;   // 2 thr/row, 16 elem each
  f32x4 acc[4][4] = {};

  for (int k0 = 0; k0 < K; k0 += 32) {
    __align__(16) u16 abuf[16], bbuf[16];
    if constexpr (AF32) {
      const float* gA = (const float*)Ap + (size_t)(bm + srow) * lda + scol + k0;
      union { float4 v[4]; float s[16]; } fa;
#pragma unroll
      for (int j = 0; j < 4; j++) fa.v[j] = *(const float4*)(gA + j * 4);
#pragma unroll
      for (int j = 0; j < 16; j++) abuf[j] = f2b(fa.s[j]);
    } else {
      const u16* gA = (const u16*)Ap + (size_t)(bm + srow) * lda + scol + k0;
      *(uint4*)&abuf[0] = *(const uint4*)(gA);
      *(uint4*)&abuf[8] = *(const uint4*)(gA + 8);
    }
    if constexpr (BF32) {
      const float* gB = (const float*)Bp + (size_t)(bn + srow) * K + scol + k0;
      union { float4 v[4]; float s[16]; } fb;
#pragma unroll
      for (int j = 0; j < 4; j++) fb.v[j] = *(const float4*)(gB + j * 4);
#pragma unroll
      for (int j = 0; j < 16; j++) bbuf[j] = f2b(fb.s[j]);
    } else {
      const u16* gB = (const u16*)Bp + (size_t)(bn + srow) * K + scol + k0;
      *(uint4*)&bbuf[0] = *(const uint4*)(gB);
      *(uint4*)&bbuf[8] = *(const uint4*)(gB + 8);
    }
    __syncthreads();                       // prior-iter LDS reads done
    *(uint4*)&lA[srow * 32 + scol]     = *(uint4*)&abuf[0];
    *(uint4*)&lA[srow * 32 + scol + 8] = *(uint4*)&abuf[8];
    *(uint4*)&lB[srow * 32 + scol]     = *(uint4*)&bbuf[0];
    *(uint4*)&lB[srow * 32 + scol + 8] = *(uint4*)&bbuf[8];
    __syncthreads();
    bf16x8 af[4], bfv[4];
#pragma unroll
    for (int i = 0; i < 4; i++)
      af[i] = *(const bf16x8*)&lA[(wm + i * 16 + l16) * 32 + quad * 8];
#pragma unroll
    for (int i = 0; i < 4; i++)
      bfv[i] = *(const bf16x8*)&lB[(wn + i * 16 + l16) * 32 + quad * 8];
#pragma unroll
    for (int i = 0; i < 4; i++)
#pragma unroll
      for (int j = 0; j < 4; j++)
        acc[i][j] = MFMA16(af[i], bfv[j], acc[i][j]);
  }
  // C/D layout: col = lane&15, row = quad*4 + reg  [m89/m91 verified]
#pragma unroll
  for (int i = 0; i < 4; i++) {
#pragma unroll
    for (int r = 0; r < 4; r++) {
      const int row = bm + wm + i * 16 + quad * 4 + r;
      if constexpr (OUTF32) {
        float* crow = (float*)Cp + (size_t)row * N + bn + wn + l16;
#pragma unroll
        for (int j = 0; j < 4; j++)
          crow[j * 16] = acc[i][j][r];
      } else {
        u16* crow = (u16*)Cp + (size_t)row * N + bn + wn + l16;
#pragma unroll
        for (int j = 0; j < 4; j++)
          crow[j * 16] = f2b(acc[i][j][r]);
      }
    }
  }
}

// ---------------------------------------------------------------------------
// Adapter pqkv: ak/av[h][l][d] = bf16(adapter_emb[l]) . bf16(W_attn[...]),
// fp32 accum/out (160 KiB scratch in d_out, dead before proj overwrites).
// ---------------------------------------------------------------------------
__global__ __launch_bounds__(256) void adapter_pqkv(
    const float* __restrict__ emb, const float* __restrict__ W,
    float* __restrict__ akb, float* __restrict__ avb)
{
  const int tid = threadIdx.x;
  const int lane = tid & 63;
  const int w = blockIdx.x * 4 + (tid >> 6);      // 0..4095
  const int part = w >> 11;                        // 0 = k, 1 = v
  const int col = w & 2047;                        // h*128 + d
  const float* wrow = W + (size_t)(C_ + part * C_ + col) * C_;
  float acc[AL_];
#pragma unroll
  for (int l = 0; l < AL_; l++) acc[l] = 0.f;
  for (int i = 0; i < 32; i++) {
    const int c = i * 64 + lane;
    const float wv = rb(wrow[c]);
#pragma unroll
    for (int l = 0; l < AL_; l++) acc[l] += wv * rb(emb[l * C_ + c]);
  }
#pragma unroll
  for (int l = 0; l < AL_; l++) {
    for (int off = 32; off > 0; off >>= 1) acc[l] += __shfl_xor(acc[l], off);
  }
  if (lane == 0) {
    const int h = col >> 7, d = col & 127;
    float* dst = (part == 0 ? akb : avb) + (size_t)h * AL_ * HS_ + d;
#pragma unroll
    for (int l = 0; l < AL_; l++) dst[l * HS_] = acc[l];
  }
}

// ---------------------------------------------------------------------------
// RoPE in-place on qkv's q and k parts (qkv is bf16). rope table is FP32.
// ---------------------------------------------------------------------------
__global__ __launch_bounds__(256) void rope_inplace(
    u16* __restrict__ qkv, const float* __restrict__ rope)
{
  const int g = blockIdx.x * 256 + threadIdx.x;
  const int j2 = g & 63;
  const int h  = (g >> 6) & 15;
  const int t  = (g >> 10) & 2047;
  const int b  = g >> 21;
  u16* src = qkv + (size_t)(b * T_ + t) * C3_ + h * HS_ + j2 * 2;
  const u32 qp = *(const u32*)(src);
  const u32 kp = *(const u32*)(src + C_);
  const float2 rp = *(const float2*)(rope + (t * 64 + j2) * 2);
  const float c = rb(rp.x), s = rb(rp.y);
  const float q0 = b2f((u16)qp), q1 = b2f((u16)(qp >> 16));
  const float k0 = b2f((u16)kp), k1 = b2f((u16)(kp >> 16));
  const float qr0 = q0 * c - q1 * s, qr1 = q1 * c + q0 * s;
  const float kr0 = k0 * c - k1 * s, kr1 = k1 * c + k0 * s;
  *(u32*)(src)      = (u32)f2b(qr0) | ((u32)f2b(qr1) << 16);
  *(u32*)(src + C_) = (u32)f2b(kr0) | ((u32)f2b(kr1) << 16);
}

// ---------------------------------------------------------------------------
// V transpose: vt[b][h][d][t] = qkv v-part (bf16). 64t x 128d tiles via
// swizzled LDS (rows 256B, byte ^= (t&7)<<4 -> conflict-free b128 staging).
// ~32 MiB traffic total; removes the conflict-heavy in-attn V scatter.
// ---------------------------------------------------------------------------
__global__ __launch_bounds__(256) void transpose_v(
    const u16* __restrict__ qkv, u16* __restrict__ vt)
{
  __shared__ __align__(16) char lT[64 * 256];
  const int tid = threadIdx.x;
  const int t0 = blockIdx.x * 64, h = blockIdx.y, b = blockIdx.z;
  const u16* Vg = qkv + (size_t)(b * T_ + t0) * C3_ + 2 * C_ + h * HS_;
#pragma unroll
  for (int i = 0; i < 4; i++) {
    const int e = (i * 256 + tid) * 8;      // u16 linear index in 64x128
    const int t = e >> 7, c = e & 127;
    *(uint4*)(lT + t * 256 + ((c * 2) ^ ((t & 7) << 4))) =
        *(const uint4*)(Vg + (size_t)t * C3_ + c);
  }
  __syncthreads();
  const int d = tid >> 1, half = tid & 1;
  __align__(16) u16 out[32];
#pragma unroll
  for (int tt = 0; tt < 32; tt++) {
    const int t = half * 32 + tt;
    out[tt] = *(const u16*)(lT + t * 256 + ((d * 2) ^ ((t & 7) << 4)));
  }
  u16* dst = vt + ((size_t)(b * H_ + h) * HS_ + d) * T_ + t0 + half * 32;
  *(uint4*)(dst)      = *(const uint4*)&out[0];
  *(uint4*)(dst + 8)  = *(const uint4*)&out[8];
  *(uint4*)(dst + 16) = *(const uint4*)&out[16];
  *(uint4*)(dst + 24) = *(const uint4*)&out[24];
}

// ---------------------------------------------------------------------------
// Flash attention + gated adapter attention.
//  - lQ/lK: row stride 256B, XOR-swizzled (byte ^= (row&7)<<4) on BOTH write
//    and read -> conflict-free ds_read_b128 (was ~16-way).
//  - V staged from pre-transposed vt[b][h][d][t], LDS stride 40 u16 (80B)
//    -> conflict-free staging writes AND PV reads (was 8-16-way + scatter).
//  - lP: stride 40 u16 -> conflict-free PV A-reads.
//  - qt = 15 - blockIdx.x: heavy causal blocks dispatch first (tail fix).
//  - adapter: 2 thr/row, vectorized lQ b128 reads, ak/av staged in LDS,
//    lAy overlays dead lQ.
// y written IN-PLACE over qkv's q-part (block-private patch).
// ---------------------------------------------------------------------------
__global__ __launch_bounds__(256) void attn_flash(
    u16* __restrict__ qkv, const u16* __restrict__ vt,
    const float* __restrict__ akbuf, const float* __restrict__ avbuf,
    const float* __restrict__ gating)
{
  __shared__ __align__(16) char smem[61440];
  char* smQ = smem;                    // [0,32768)   128 rows x 256B swizzled
  char* smK = smem + 32768;            // [32768,40960)  32 rows x 256B swizzled
  char* smV = smem + 40960;            // [40960,51200)  Vt: 128 d-rows x 80B
  char* smP = smem + 51200;            // [51200,61440)  P: 128 rows x 80B

  const int tid  = threadIdx.x;
  const int lane = tid & 63, wave = tid >> 6;
  const int quad = lane >> 4, l16 = lane & 15;
  const int qt = 15 - (int)blockIdx.x, h = blockIdx.y, b = blockIdx.z;
  u16* Qg = qkv + ((size_t)(b * T_) + qt * 128) * C3_ + h * HS_;          // q-part
  const u16* Kg = qkv + (size_t)(b * T_) * C3_ + C_ + h * HS_;            // k-part
  const u16* Vt = vt + (size_t)(b * H_ + h) * HS_ * T_;
  const float scale = 0.08838834764831845f;   // 1/sqrt(128)

#pragma unroll
  for (int i = 0; i < 8; i++) {                // Q tile, swizzled rows
    const int e = (i * 256 + tid) * 8;
    const int row = e >> 7, col = e & 127;
    *(uint4*)(smQ + row * 256 + ((col * 2) ^ ((row & 7) << 4))) =
        *(const uint4*)(Qg + (size_t)row * C3_ + col);
  }
  f32x4 acc[2][8] = {};
  float mst[2][4], lst[2][4];
#pragma unroll
  for (int mt = 0; mt < 2; mt++)
#pragma unroll
    for (int r = 0; r < 4; r++) { mst[mt][r] = MASKV; lst[mt][r] = 0.f; }

  const int nkt = (qt + 1) * 4;
  const int krow = tid >> 3, kcolb = (tid & 7) * 32;   // K staging (byte col)
  const int ksw = (krow & 7) << 4;
  for (int kt = 0; kt < nkt; kt++) {
    __syncthreads();                           // prior-iter lK/lV/lP reads done
    {
      const u16* ks = Kg + (size_t)(kt * 32 + krow) * C3_ + (kcolb >> 1);
      char* kb = smK + krow * 256;
      *(uint4*)(kb + ((kcolb)      ^ ksw)) = *(const uint4*)(ks);
      *(uint4*)(kb + ((kcolb + 16) ^ ksw)) = *(const uint4*)(ks + 8);
      // Vt tile: 128 d-rows x 32 keys, coalesced 64B-per-4-lanes reads
#pragma unroll
      for (int it = 0; it < 2; it++) {
        const int d = it * 64 + (tid >> 2), c = tid & 3;
        *(uint4*)(smV + d * 80 + c * 16) =
            *(const uint4*)(Vt + (size_t)d * T_ + kt * 32 + c * 8);
      }
    }
    __syncthreads();
    // ---- S = Q K^T ----
    f32x4 sacc[2][2] = {};
    const int sw = (l16 & 7) << 4;
#pragma unroll
    for (int kk = 0; kk < 4; kk++) {
      const int co = (kk * 64 + quad * 16) ^ sw;
      bf16x8 aq0 = *(const bf16x8*)(smQ + (wave * 32 + l16) * 256 + co);
      bf16x8 aq1 = *(const bf16x8*)(smQ + (wave * 32 + 16 + l16) * 256 + co);
      bf16x8 bk0 = *(const bf16x8*)(smK + l16 * 256 + co);
      bf16x8 bk1 = *(const bf16x8*)(smK + (16 + l16) * 256 + co);
      sacc[0][0] = MFMA16(aq0, bk0, sacc[0][0]);
      sacc[0][1] = MFMA16(aq0, bk1, sacc[0][1]);
      sacc[1][0] = MFMA16(aq1, bk0, sacc[1][0]);
      sacc[1][1] = MFMA16(aq1, bk1, sacc[1][1]);
    }
    // ---- online softmax ----
#pragma unroll
    for (int mt = 0; mt < 2; mt++) {
      float p0[4], p1[4], alpha[4];
#pragma unroll
      for (int r = 0; r < 4; r++) {
        const int qg = qt * 128 + wave * 32 + mt * 16 + quad * 4 + r;
        float s0 = sacc[mt][0][r] * scale;
        float s1 = sacc[mt][1][r] * scale;
        if (kt * 32 + l16 > qg)      s0 = MASKV;
        if (kt * 32 + 16 + l16 > qg) s1 = MASKV;
        float rmax = fmaxf(s0, s1);
#pragma unroll
        for (int off = 1; off < 16; off <<= 1)
          rmax = fmaxf(rmax, __shfl_xor(rmax, off));
        const float mnew = fmaxf(mst[mt][r], rmax);
        alpha[r] = __expf(mst[mt][r] - mnew);
        mst[mt][r] = mnew;
        p0[r] = __expf(s0 - mnew);
        p1[r] = __expf(s1 - mnew);
        float rs = p0[r] + p1[r];
#pragma unroll
        for (int off = 1; off < 16; off <<= 1)
          rs += __shfl_xor(rs, off);
        lst[mt][r] = lst[mt][r] * alpha[r] + rs;
      }
#pragma unroll
      for (int r = 0; r < 4; r++) {            // P: C-layout -> row-major LDS
        const int row = wave * 32 + mt * 16 + quad * 4 + r;
        *(u16*)(smP + row * 80 + l16 * 2)      = f2b(p0[r]);
        *(u16*)(smP + row * 80 + 32 + l16 * 2) = f2b(p1[r]);
      }
#pragma unroll
      for (int nt = 0; nt < 8; nt++)           // rescale O (lane-local alpha)
#pragma unroll
        for (int r = 0; r < 4; r++) acc[mt][nt][r] *= alpha[r];
    }
    // ---- fence: u16 P-stores ordered before bf16x8 P-loads ----
    __syncthreads();
    // ---- O += P V ----
#pragma unroll
    for (int mt = 0; mt < 2; mt++) {
      bf16x8 ap = *(const bf16x8*)(smP + (wave * 32 + mt * 16 + l16) * 80 + quad * 16);
#pragma unroll
      for (int nt = 0; nt < 8; nt++) {
        bf16x8 bv = *(const bf16x8*)(smV + (nt * 16 + l16) * 80 + quad * 16);
        acc[mt][nt] = MFMA16(ap, bv, acc[mt][nt]);
      }
    }
  }
  // ---- adapter attention (10 prefix keys, separate softmax) ----
  __syncthreads();                             // all PV reads done; lK/lV/lP dead
  float* lAk = (float*)smK;                    // overlay [32768,43008)
  float* lAv = lAk + AL_ * HS_;
  {
    const float* aks = akbuf + (size_t)h * AL_ * HS_;
    const float* avs = avbuf + (size_t)h * AL_ * HS_;
    for (int i = tid; i < AL_ * HS_; i += 256) { lAk[i] = aks[i]; lAv[i] = avs[i]; }
  }
  __syncthreads();
  const int ar = tid >> 1, ah = tid & 1;       // 2 threads per q-row
  const int asw = (ar & 7) << 4;
  float sa[AL_];
#pragma unroll
  for (int l = 0; l < AL_; l++) sa[l] = 0.f;
#pragma unroll
  for (int c = 0; c < 8; c++) {                // own half of d, b128 reads
    const int col = ah * 64 + c * 8;
    union { uint4 v; u16 e[8]; } qv;
    qv.v = *(const uint4*)(smQ + ar * 256 + ((col * 2) ^ asw));
#pragma unroll
    for (int j = 0; j < 8; j++) {
      const float qf = b2f(qv.e[j]);
#pragma unroll
      for (int l = 0; l < AL_; l++) sa[l] += qf * lAk[l * HS_ + col + j];
    }
  }
#pragma unroll
  for (int l = 0; l < AL_; l++) sa[l] = (sa[l] + __shfl_xor(sa[l], 1)) * scale;
  float smax = sa[0];
#pragma unroll
  for (int l = 1; l < AL_; l++) smax = fmaxf(smax, sa[l]);
  float ssum = 0.f;
#pragma unroll
  for (int l = 0; l < AL_; l++) { sa[l] = __expf(sa[l] - smax); ssum += sa[l]; }
  const float inv = 1.f / ssum;
#pragma unroll
  for (int l = 0; l < AL_; l++) sa[l] *= inv;
  __syncthreads();                             // all lQ reads done -> overlay lAy
  u16* lAy = (u16*)smem;                       // 128 x 128, linear
#pragma unroll
  for (int c = 0; c < 8; c++) {
    const int col = ah * 64 + c * 8;
    union { uint4 v; u16 e[8]; } ov;
#pragma unroll
    for (int j = 0; j < 8; j++) {
      float a = 0.f;
#pragma unroll
      for (int l = 0; l < AL_; l++) a += sa[l] * lAv[l * HS_ + col + j];
      ov.e[j] = f2b(a);
    }
    *(uint4*)(lAy + ar * HS_ + col) = ov.v;
  }
  __syncthreads();
  // ---- epilogue: y = O/l + g*ay, written over qkv q-part (block's own patch)
  const float g = rb(gating[h]);
#pragma unroll
  for (int mt = 0; mt < 2; mt++) {
#pragma unroll
    for (int r = 0; r < 4; r++) {
      const int row = wave * 32 + mt * 16 + quad * 4 + r;
      const float linv = 1.f / lst[mt][r];
      u16* yrow = Qg + (size_t)row * C3_ + l16;
#pragma unroll
      for (int nt = 0; nt < 8; nt++) {
        const float v = acc[mt][nt][r] * linv + g * b2f(lAy[row * HS_ + nt * 16 + l16]);
        yrow[nt * 16] = f2b(v);
      }
    }
  }
}

// ---------------------------------------------------------------------------
extern "C" void kernel_launch(void* const* d_in, const int* in_sizes, int n_in,
                              void* d_out, int out_size, void* d_ws, size_t ws_size,
                              hipStream_t stream) {
  (void)out_size; (void)ws_size;
  // Inputs are FP32, dict order; bind by unique element count with dict-order
  // fallbacks. W_proj = LAST 4194304-elem input (mask idx 2 < W_proj idx 4).
  int ix = 0, irope = 1, iW = 3, iP = 4, iE = 5, iG = 6;
  for (int i = 0; i < n_in; i++) {
    switch (in_sizes[i]) {
      case 8388608:  ix = i;    break;   // x (2,2048,2048)
      case 262144:   irope = i; break;   // rope (2048,64,2)
      case 12582912: iW = i;    break;   // W_attn (6144,2048)
      case 20480:    iE = i;    break;   // adapter_emb (10,2048)
      case 16:       iG = i;    break;   // gating (1,16,1,1)
      case 4194304:  iP = i;    break;   // mask (idx 2) then W_proj (idx 4): last wins
      default: break;
    }
  }
  const float* x      = (const float*)d_in[ix];
  const float* rope   = (const float*)d_in[irope];
  const float* W_attn = (const float*)d_in[iW];
  const float* W_proj = (const float*)d_in[iP];
  const float* emb    = (const float*)d_in[iE];
  const float* gating = (const float*)d_in[iG];

  // Workspace: qkv bf16, 48 MiB. d_out (32 MiB, dead until proj GEMM) hosts:
  //   [0,160KiB)      ak/av fp32 adapter scratch
  //   [160KiB,+16MiB) vt = V^T bf16 [b][h][d][t]
  u16*   qkv = (u16*)d_ws;
  float* akb = (float*)d_out;
  float* avb = akb + (size_t)H_ * AL_ * HS_;
  u16*   vtb = (u16*)(avb + (size_t)H_ * AL_ * HS_);

  // qkv = bf16(x) @ bf16(W_attn)^T   (M=4096, N=6144, K=2048), bf16 out
  gemm_nt<true, true, false><<<dim3(48, 32), 256, 0, stream>>>(
      x, W_attn, qkv, 6144, 2048, 2048);
  adapter_pqkv<<<dim3(1024), 256, 0, stream>>>(emb, W_attn, akb, avb);
  rope_inplace<<<dim3(16384), 256, 0, stream>>>(qkv, rope);
  transpose_v<<<dim3(32, 16, 2), 256, 0, stream>>>(qkv, vtb);
  attn_flash<<<dim3(16, 16, 2), 256, 0, stream>>>(qkv, vtb, akb, avb, gating);
  // out = y @ bf16(W_proj)^T   (A = y bf16 strided in qkv, lda=6144), FP32 out
  gemm_nt<false, true, true><<<dim3(16, 32), 256, 0, stream>>>(
      qkv, W_proj, (float*)d_out, 2048, 2048, 6144);
}

// Round 2
// 709.435 us; speedup vs baseline: 1.3234x; 1.2388x over previous
//
#include <hip/hip_runtime.h>

typedef unsigned short u16;
typedef unsigned int u32;
typedef __bf16 bf16x8 __attribute__((ext_vector_type(8)));
typedef float f32x4 __attribute__((ext_vector_type(4)));

#define B_ 2
#define T_ 2048
#define C_ 2048
#define H_ 16
#define HS_ 128
#define AL_ 10
#define C3_ 6144
#define MASKV (-3.0e38f)   // finite "-inf": exp(MASKV - m) == 0
#define MFMA16(a, b, c) __builtin_amdgcn_mfma_f32_16x16x32_bf16(a, b, c, 0, 0, 0)

// async global->LDS DMA, 16B per lane. LDS dest = wave-uniform base + lane*16;
// global src is per-lane. size MUST be a literal (guide: Common-mistake #1).
#define GLDS16(g, l) __builtin_amdgcn_global_load_lds(                         \
    (const __attribute__((address_space(1))) u32*)(const void*)(g),            \
    (__attribute__((address_space(3))) u32*)(void*)(l), 16, 0, 0)

__device__ __forceinline__ float b2f(u16 v) {
  union { u32 u; float f; } x; x.u = ((u32)v) << 16; return x.f;
}
__device__ __forceinline__ u16 f2b(float f) {
  u32 u = __builtin_bit_cast(u32, f);
  return (u16)((u + 0x7FFFu + ((u >> 16) & 1u)) >> 16);  // RNE
}
// fp32 -> bf16 -> fp32 (match the np ref's bf16-cast of fp32 inputs)
__device__ __forceinline__ float rb(float f) { return b2f(f2b(f)); }

// ---------------------------------------------------------------------------
// f32 -> bf16 bulk convert, 8 elem/thread (16B out per lane).
// ---------------------------------------------------------------------------
__global__ __launch_bounds__(256) void f32_to_bf16(
    const float* __restrict__ in, u16* __restrict__ out, int n8)
{
  const int i = blockIdx.x * 256 + threadIdx.x;
  if (i >= n8) return;
  union { float4 v[2]; float s[8]; } f;
  f.v[0] = *(const float4*)(in + (size_t)i * 8);
  f.v[1] = *(const float4*)(in + (size_t)i * 8 + 4);
  union { uint4 v; u16 e[8]; } o;
#pragma unroll
  for (int j = 0; j < 8; j++) o.e[j] = f2b(f.s[j]);
  *(uint4*)(out + (size_t)i * 8) = o.v;
}

// ---------------------------------------------------------------------------
// Fast GEMM (m97 structure): C(MxN) = A(MxK) * B(NxK)^T, both bf16, fp32
// accum. 128x128 tile, BK=32, 4 waves x 64x64 quadrant, global_load_lds
// width-16 staging (linear LDS, wave base + lane*16), 2 barriers/iter,
// bijective XCD swizzle (grid total % 8 == 0 for both uses).
// ---------------------------------------------------------------------------
template <bool OUTF32>
__global__ __launch_bounds__(256) void gemm_lds(
    const u16* __restrict__ Ap, const u16* __restrict__ Bp,
    void* __restrict__ Cp, int N, int K, int lda)
{
  __shared__ u16 lA[128 * 32];
  __shared__ u16 lB[128 * 32];
  const int tid  = threadIdx.x;
  const int lane = tid & 63, wave = tid >> 6;
  const int quad = lane >> 4, l16 = lane & 15;
  // XCD-aware swizzle: consecutive swizzled ids share an XCD -> A/B panel L2 hits
  const int nwg = gridDim.x * gridDim.y;
  int bid = blockIdx.y * gridDim.x + blockIdx.x;
  bid = (bid & 7) * (nwg >> 3) + (bid >> 3);
  const int bm = (bid / gridDim.x) * 128, bn = (bid % gridDim.x) * 128;
  const int wm = (wave >> 1) * 64, wn = (wave & 1) * 64;

  // staging map: LDS byte = wave*1024 + j*4096 + lane*16
  //   -> row = j*64 + wave*16 + (lane>>2), col(u16) = (lane&3)*8
  const int r0 = wave * 16 + (lane >> 2);
  const int c0 = (lane & 3) * 8;
  const u16* ga0 = Ap + (size_t)(bm + r0) * lda + c0;
  const u16* ga1 = ga0 + (size_t)64 * lda;
  const u16* gb0 = Bp + (size_t)(bn + r0) * K + c0;
  const u16* gb1 = gb0 + (size_t)64 * K;
  u16* la0 = &lA[wave * 512];
  u16* lb0 = &lB[wave * 512];

  f32x4 acc[4][4] = {};
  for (int k0 = 0; k0 < K; k0 += 32) {
    __syncthreads();                       // prior-iter LDS reads done
    GLDS16(ga0, la0);
    GLDS16(ga1, la0 + 2048);
    GLDS16(gb0, lb0);
    GLDS16(gb1, lb0 + 2048);
    ga0 += 32; ga1 += 32; gb0 += 32; gb1 += 32;
    __syncthreads();                       // DMA landed (syncthreads drains vmcnt)
    bf16x8 af[4], bfv[4];
#pragma unroll
    for (int i = 0; i < 4; i++)
      af[i] = *(const bf16x8*)&lA[(wm + i * 16 + l16) * 32 + quad * 8];
#pragma unroll
    for (int i = 0; i < 4; i++)
      bfv[i] = *(const bf16x8*)&lB[(wn + i * 16 + l16) * 32 + quad * 8];
#pragma unroll
    for (int i = 0; i < 4; i++)
#pragma unroll
      for (int j = 0; j < 4; j++)
        acc[i][j] = MFMA16(af[i], bfv[j], acc[i][j]);
  }
  // C/D layout: col = lane&15, row = quad*4 + reg  [m89/m91 verified]
#pragma unroll
  for (int i = 0; i < 4; i++) {
#pragma unroll
    for (int r = 0; r < 4; r++) {
      const int row = bm + wm + i * 16 + quad * 4 + r;
      if constexpr (OUTF32) {
        float* crow = (float*)Cp + (size_t)row * N + bn + wn + l16;
#pragma unroll
        for (int j = 0; j < 4; j++)
          crow[j * 16] = acc[i][j][r];
      } else {
        u16* crow = (u16*)Cp + (size_t)row * N + bn + wn + l16;
#pragma unroll
        for (int j = 0; j < 4; j++)
          crow[j * 16] = f2b(acc[i][j][r]);
      }
    }
  }
}

// ---------------------------------------------------------------------------
// Fallback GEMM (used only if ws_size can't host bf16 copies):
// C(MxN) = A(MxK) * B(NxK)^T with in-loop f32->bf16 conversion.
// ---------------------------------------------------------------------------
template <bool AF32, bool BF32, bool OUTF32>
__global__ __launch_bounds__(256) void gemm_nt(
    const void* __restrict__ Ap, const void* __restrict__ Bp,
    void* __restrict__ Cp, int N, int K, int lda)
{
  __shared__ u16 lA[128 * 32];
  __shared__ u16 lB[128 * 32];
  const int tid  = threadIdx.x;
  const int lane = tid & 63, wave = tid >> 6;
  const int quad = lane >> 4, l16 = lane & 15;
  const int bm = blockIdx.y * 128, bn = blockIdx.x * 128;
  const int wm = (wave >> 1) * 64, wn = (wave & 1) * 64;
  const int srow = tid >> 1, scol = (tid & 1) * 16;   // 2 thr/row, 16 elem each
  f32x4 acc[4][4] = {};

  for (int k0 = 0; k0 < K; k0 += 32) {
    __align__(16) u16 abuf[16], bbuf[16];
    if constexpr (AF32) {
      const float* gA = (const float*)Ap + (size_t)(bm + srow) * lda + scol + k0;
      union { float4 v[4]; float s[16]; } fa;
#pragma unroll
      for (int j = 0; j < 4; j++) fa.v[j] = *(const float4*)(gA + j * 4);
#pragma unroll
      for (int j = 0; j < 16; j++) abuf[j] = f2b(fa.s[j]);
    } else {
      const u16* gA = (const u16*)Ap + (size_t)(bm + srow) * lda + scol + k0;
      *(uint4*)&abuf[0] = *(const uint4*)(gA);
      *(uint4*)&abuf[8] = *(const uint4*)(gA + 8);
    }
    if constexpr (BF32) {
      const float* gB = (const float*)Bp + (size_t)(bn + srow) * K + scol + k0;
      union { float4 v[4]; float s[16]; } fb;
#pragma unroll
      for (int j = 0; j < 4; j++) fb.v[j] = *(const float4*)(gB + j * 4);
#pragma unroll
      for (int j = 0; j < 16; j++) bbuf[j] = f2b(fb.s[j]);
    } else {
      const u16* gB = (const u16*)Bp + (size_t)(bn + srow) * K + scol + k0;
      *(uint4*)&bbuf[0] = *(const uint4*)(gB);
      *(uint4*)&bbuf[8] = *(const uint4*)(gB + 8);
    }
    __syncthreads();
    *(uint4*)&lA[srow * 32 + scol]     = *(uint4*)&abuf[0];
    *(uint4*)&lA[srow * 32 + scol + 8] = *(uint4*)&abuf[8];
    *(uint4*)&lB[srow * 32 + scol]     = *(uint4*)&bbuf[0];
    *(uint4*)&lB[srow * 32 + scol + 8] = *(uint4*)&bbuf[8];
    __syncthreads();
    bf16x8 af[4], bfv[4];
#pragma unroll
    for (int i = 0; i < 4; i++)
      af[i] = *(const bf16x8*)&lA[(wm + i * 16 + l16) * 32 + quad * 8];
#pragma unroll
    for (int i = 0; i < 4; i++)
      bfv[i] = *(const bf16x8*)&lB[(wn + i * 16 + l16) * 32 + quad * 8];
#pragma unroll
    for (int i = 0; i < 4; i++)
#pragma unroll
      for (int j = 0; j < 4; j++)
        acc[i][j] = MFMA16(af[i], bfv[j], acc[i][j]);
  }
#pragma unroll
  for (int i = 0; i < 4; i++) {
#pragma unroll
    for (int r = 0; r < 4; r++) {
      const int row = bm + wm + i * 16 + quad * 4 + r;
      if constexpr (OUTF32) {
        float* crow = (float*)Cp + (size_t)row * N + bn + wn + l16;
#pragma unroll
        for (int j = 0; j < 4; j++)
          crow[j * 16] = acc[i][j][r];
      } else {
        u16* crow = (u16*)Cp + (size_t)row * N + bn + wn + l16;
#pragma unroll
        for (int j = 0; j < 4; j++)
          crow[j * 16] = f2b(acc[i][j][r]);
      }
    }
  }
}

// ---------------------------------------------------------------------------
// Adapter pqkv: ak/av[h][l][d] = bf16(adapter_emb[l]) . bf16(W_attn[...]),
// fp32 accum/out (160 KiB scratch in d_out, dead before proj overwrites).
// ---------------------------------------------------------------------------
__global__ __launch_bounds__(256) void adapter_pqkv(
    const float* __restrict__ emb, const float* __restrict__ W,
    float* __restrict__ akb, float* __restrict__ avb)
{
  const int tid = threadIdx.x;
  const int lane = tid & 63;
  const int w = blockIdx.x * 4 + (tid >> 6);      // 0..4095
  const int part = w >> 11;                        // 0 = k, 1 = v
  const int col = w & 2047;                        // h*128 + d
  const float* wrow = W + (size_t)(C_ + part * C_ + col) * C_;
  float acc[AL_];
#pragma unroll
  for (int l = 0; l < AL_; l++) acc[l] = 0.f;
  for (int i = 0; i < 32; i++) {
    const int c = i * 64 + lane;
    const float wv = rb(wrow[c]);
#pragma unroll
    for (int l = 0; l < AL_; l++) acc[l] += wv * rb(emb[l * C_ + c]);
  }
#pragma unroll
  for (int l = 0; l < AL_; l++) {
    for (int off = 32; off > 0; off >>= 1) acc[l] += __shfl_xor(acc[l], off);
  }
  if (lane == 0) {
    const int h = col >> 7, d = col & 127;
    float* dst = (part == 0 ? akb : avb) + (size_t)h * AL_ * HS_ + d;
#pragma unroll
    for (int l = 0; l < AL_; l++) dst[l * HS_] = acc[l];
  }
}

// ---------------------------------------------------------------------------
// RoPE in-place on qkv's q and k parts (qkv is bf16). rope table is FP32.
// ---------------------------------------------------------------------------
__global__ __launch_bounds__(256) void rope_inplace(
    u16* __restrict__ qkv, const float* __restrict__ rope)
{
  const int g = blockIdx.x * 256 + threadIdx.x;
  const int j2 = g & 63;
  const int h  = (g >> 6) & 15;
  const int t  = (g >> 10) & 2047;
  const int b  = g >> 21;
  u16* src = qkv + (size_t)(b * T_ + t) * C3_ + h * HS_ + j2 * 2;
  const u32 qp = *(const u32*)(src);
  const u32 kp = *(const u32*)(src + C_);
  const float2 rp = *(const float2*)(rope + (t * 64 + j2) * 2);
  const float c = rb(rp.x), s = rb(rp.y);
  const float q0 = b2f((u16)qp), q1 = b2f((u16)(qp >> 16));
  const float k0 = b2f((u16)kp), k1 = b2f((u16)(kp >> 16));
  const float qr0 = q0 * c - q1 * s, qr1 = q1 * c + q0 * s;
  const float kr0 = k0 * c - k1 * s, kr1 = k1 * c + k0 * s;
  *(u32*)(src)      = (u32)f2b(qr0) | ((u32)f2b(qr1) << 16);
  *(u32*)(src + C_) = (u32)f2b(kr0) | ((u32)f2b(kr1) << 16);
}

// ---------------------------------------------------------------------------
// V transpose: vt[b][h][d][t] = qkv v-part (bf16). 64t x 128d tiles via
// swizzled LDS (rows 256B, byte ^= (t&7)<<4 -> conflict-free b128 staging).
// ---------------------------------------------------------------------------
__global__ __launch_bounds__(256) void transpose_v(
    const u16* __restrict__ qkv, u16* __restrict__ vt)
{
  __shared__ __align__(16) char lT[64 * 256];
  const int tid = threadIdx.x;
  const int t0 = blockIdx.x * 64, h = blockIdx.y, b = blockIdx.z;
  const u16* Vg = qkv + (size_t)(b * T_ + t0) * C3_ + 2 * C_ + h * HS_;
#pragma unroll
  for (int i = 0; i < 4; i++) {
    const int e = (i * 256 + tid) * 8;      // u16 linear index in 64x128
    const int t = e >> 7, c = e & 127;
    *(uint4*)(lT + t * 256 + ((c * 2) ^ ((t & 7) << 4))) =
        *(const uint4*)(Vg + (size_t)t * C3_ + c);
  }
  __syncthreads();
  const int d = tid >> 1, half = tid & 1;
  __align__(16) u16 out[32];
#pragma unroll
  for (int tt = 0; tt < 32; tt++) {
    const int t = half * 32 + tt;
    out[tt] = *(const u16*)(lT + t * 256 + ((d * 2) ^ ((t & 7) << 4)));
  }
  u16* dst = vt + ((size_t)(b * H_ + h) * HS_ + d) * T_ + t0 + half * 32;
  *(uint4*)(dst)      = *(const uint4*)&out[0];
  *(uint4*)(dst + 8)  = *(const uint4*)&out[8];
  *(uint4*)(dst + 16) = *(const uint4*)&out[16];
  *(uint4*)(dst + 24) = *(const uint4*)&out[24];
}

// ---------------------------------------------------------------------------
// Flash attention + gated adapter attention (unchanged this round).
// ---------------------------------------------------------------------------
__global__ __launch_bounds__(256) void attn_flash(
    u16* __restrict__ qkv, const u16* __restrict__ vt,
    const float* __restrict__ akbuf, const float* __restrict__ avbuf,
    const float* __restrict__ gating)
{
  __shared__ __align__(16) char smem[61440];
  char* smQ = smem;                    // [0,32768)   128 rows x 256B swizzled
  char* smK = smem + 32768;            // [32768,40960)  32 rows x 256B swizzled
  char* smV = smem + 40960;            // [40960,51200)  Vt: 128 d-rows x 80B
  char* smP = smem + 51200;            // [51200,61440)  P: 128 rows x 80B

  const int tid  = threadIdx.x;
  const int lane = tid & 63, wave = tid >> 6;
  const int quad = lane >> 4, l16 = lane & 15;
  const int qt = 15 - (int)blockIdx.x, h = blockIdx.y, b = blockIdx.z;
  u16* Qg = qkv + ((size_t)(b * T_) + qt * 128) * C3_ + h * HS_;          // q-part
  const u16* Kg = qkv + (size_t)(b * T_) * C3_ + C_ + h * HS_;            // k-part
  const u16* Vt = vt + (size_t)(b * H_ + h) * HS_ * T_;
  const float scale = 0.08838834764831845f;   // 1/sqrt(128)

#pragma unroll
  for (int i = 0; i < 8; i++) {                // Q tile, swizzled rows
    const int e = (i * 256 + tid) * 8;
    const int row = e >> 7, col = e & 127;
    *(uint4*)(smQ + row * 256 + ((col * 2) ^ ((row & 7) << 4))) =
        *(const uint4*)(Qg + (size_t)row * C3_ + col);
  }
  f32x4 acc[2][8] = {};
  float mst[2][4], lst[2][4];
#pragma unroll
  for (int mt = 0; mt < 2; mt++)
#pragma unroll
    for (int r = 0; r < 4; r++) { mst[mt][r] = MASKV; lst[mt][r] = 0.f; }

  const int nkt = (qt + 1) * 4;
  const int krow = tid >> 3, kcolb = (tid & 7) * 32;   // K staging (byte col)
  const int ksw = (krow & 7) << 4;
  for (int kt = 0; kt < nkt; kt++) {
    __syncthreads();                           // prior-iter lK/lV/lP reads done
    {
      const u16* ks = Kg + (size_t)(kt * 32 + krow) * C3_ + (kcolb >> 1);
      char* kb = smK + krow * 256;
      *(uint4*)(kb + ((kcolb)      ^ ksw)) = *(const uint4*)(ks);
      *(uint4*)(kb + ((kcolb + 16) ^ ksw)) = *(const uint4*)(ks + 8);
      // Vt tile: 128 d-rows x 32 keys, coalesced 64B-per-4-lanes reads
#pragma unroll
      for (int it = 0; it < 2; it++) {
        const int d = it * 64 + (tid >> 2), c = tid & 3;
        *(uint4*)(smV + d * 80 + c * 16) =
            *(const uint4*)(Vt + (size_t)d * T_ + kt * 32 + c * 8);
      }
    }
    __syncthreads();
    // ---- S = Q K^T ----
    f32x4 sacc[2][2] = {};
    const int sw = (l16 & 7) << 4;
#pragma unroll
    for (int kk = 0; kk < 4; kk++) {
      const int co = (kk * 64 + quad * 16) ^ sw;
      bf16x8 aq0 = *(const bf16x8*)(smQ + (wave * 32 + l16) * 256 + co);
      bf16x8 aq1 = *(const bf16x8*)(smQ + (wave * 32 + 16 + l16) * 256 + co);
      bf16x8 bk0 = *(const bf16x8*)(smK + l16 * 256 + co);
      bf16x8 bk1 = *(const bf16x8*)(smK + (16 + l16) * 256 + co);
      sacc[0][0] = MFMA16(aq0, bk0, sacc[0][0]);
      sacc[0][1] = MFMA16(aq0, bk1, sacc[0][1]);
      sacc[1][0] = MFMA16(aq1, bk0, sacc[1][0]);
      sacc[1][1] = MFMA16(aq1, bk1, sacc[1][1]);
    }
    // ---- online softmax ----
#pragma unroll
    for (int mt = 0; mt < 2; mt++) {
      float p0[4], p1[4], alpha[4];
#pragma unroll
      for (int r = 0; r < 4; r++) {
        const int qg = qt * 128 + wave * 32 + mt * 16 + quad * 4 + r;
        float s0 = sacc[mt][0][r] * scale;
        float s1 = sacc[mt][1][r] * scale;
        if (kt * 32 + l16 > qg)      s0 = MASKV;
        if (kt * 32 + 16 + l16 > qg) s1 = MASKV;
        float rmax = fmaxf(s0, s1);
#pragma unroll
        for (int off = 1; off < 16; off <<= 1)
          rmax = fmaxf(rmax, __shfl_xor(rmax, off));
        const float mnew = fmaxf(mst[mt][r], rmax);
        alpha[r] = __expf(mst[mt][r] - mnew);
        mst[mt][r] = mnew;
        p0[r] = __expf(s0 - mnew);
        p1[r] = __expf(s1 - mnew);
        float rs = p0[r] + p1[r];
#pragma unroll
        for (int off = 1; off < 16; off <<= 1)
          rs += __shfl_xor(rs, off);
        lst[mt][r] = lst[mt][r] * alpha[r] + rs;
      }
#pragma unroll
      for (int r = 0; r < 4; r++) {            // P: C-layout -> row-major LDS
        const int row = wave * 32 + mt * 16 + quad * 4 + r;
        *(u16*)(smP + row * 80 + l16 * 2)      = f2b(p0[r]);
        *(u16*)(smP + row * 80 + 32 + l16 * 2) = f2b(p1[r]);
      }
#pragma unroll
      for (int nt = 0; nt < 8; nt++)           // rescale O (lane-local alpha)
#pragma unroll
        for (int r = 0; r < 4; r++) acc[mt][nt][r] *= alpha[r];
    }
    // ---- fence: u16 P-stores ordered before bf16x8 P-loads ----
    __syncthreads();
    // ---- O += P V ----
#pragma unroll
    for (int mt = 0; mt < 2; mt++) {
      bf16x8 ap = *(const bf16x8*)(smP + (wave * 32 + mt * 16 + l16) * 80 + quad * 16);
#pragma unroll
      for (int nt = 0; nt < 8; nt++) {
        bf16x8 bv = *(const bf16x8*)(smV + (nt * 16 + l16) * 80 + quad * 16);
        acc[mt][nt] = MFMA16(ap, bv, acc[mt][nt]);
      }
    }
  }
  // ---- adapter attention (10 prefix keys, separate softmax) ----
  __syncthreads();                             // all PV reads done; lK/lV/lP dead
  float* lAk = (float*)smK;                    // overlay [32768,43008)
  float* lAv = lAk + AL_ * HS_;
  {
    const float* aks = akbuf + (size_t)h * AL_ * HS_;
    const float* avs = avbuf + (size_t)h * AL_ * HS_;
    for (int i = tid; i < AL_ * HS_; i += 256) { lAk[i] = aks[i]; lAv[i] = avs[i]; }
  }
  __syncthreads();
  const int ar = tid >> 1, ah = tid & 1;       // 2 threads per q-row
  const int asw = (ar & 7) << 4;
  float sa[AL_];
#pragma unroll
  for (int l = 0; l < AL_; l++) sa[l] = 0.f;
#pragma unroll
  for (int c = 0; c < 8; c++) {                // own half of d, b128 reads
    const int col = ah * 64 + c * 8;
    union { uint4 v; u16 e[8]; } qv;
    qv.v = *(const uint4*)(smQ + ar * 256 + ((col * 2) ^ asw));
#pragma unroll
    for (int j = 0; j < 8; j++) {
      const float qf = b2f(qv.e[j]);
#pragma unroll
      for (int l = 0; l < AL_; l++) sa[l] += qf * lAk[l * HS_ + col + j];
    }
  }
#pragma unroll
  for (int l = 0; l < AL_; l++) sa[l] = (sa[l] + __shfl_xor(sa[l], 1)) * scale;
  float smax = sa[0];
#pragma unroll
  for (int l = 1; l < AL_; l++) smax = fmaxf(smax, sa[l]);
  float ssum = 0.f;
#pragma unroll
  for (int l = 0; l < AL_; l++) { sa[l] = __expf(sa[l] - smax); ssum += sa[l]; }
  const float inv = 1.f / ssum;
#pragma unroll
  for (int l = 0; l < AL_; l++) sa[l] *= inv;
  __syncthreads();                             // all lQ reads done -> overlay lAy
  u16* lAy = (u16*)smem;                       // 128 x 128, linear
#pragma unroll
  for (int c = 0; c < 8; c++) {
    const int col = ah * 64 + c * 8;
    union { uint4 v; u16 e[8]; } ov;
#pragma unroll
    for (int j = 0; j < 8; j++) {
      float a = 0.f;
#pragma unroll
      for (int l = 0; l < AL_; l++) a += sa[l] * lAv[l * HS_ + col + j];
      ov.e[j] = f2b(a);
    }
    *(uint4*)(lAy + ar * HS_ + col) = ov.v;
  }
  __syncthreads();
  // ---- epilogue: y = O/l + g*ay, written over qkv q-part (block's own patch)
  const float g = rb(gating[h]);
#pragma unroll
  for (int mt = 0; mt < 2; mt++) {
#pragma unroll
    for (int r = 0; r < 4; r++) {
      const int row = wave * 32 + mt * 16 + quad * 4 + r;
      const float linv = 1.f / lst[mt][r];
      u16* yrow = Qg + (size_t)row * C3_ + l16;
#pragma unroll
      for (int nt = 0; nt < 8; nt++) {
        const float v = acc[mt][nt][r] * linv + g * b2f(lAy[row * HS_ + nt * 16 + l16]);
        yrow[nt * 16] = f2b(v);
      }
    }
  }
}

// ---------------------------------------------------------------------------
extern "C" void kernel_launch(void* const* d_in, const int* in_sizes, int n_in,
                              void* d_out, int out_size, void* d_ws, size_t ws_size,
                              hipStream_t stream) {
  (void)out_size;
  // Inputs are FP32, dict order; bind by unique element count with dict-order
  // fallbacks. W_proj = LAST 4194304-elem input (mask idx 2 < W_proj idx 4).
  int ix = 0, irope = 1, iW = 3, iP = 4, iE = 5, iG = 6;
  for (int i = 0; i < n_in; i++) {
    switch (in_sizes[i]) {
      case 8388608:  ix = i;    break;   // x (2,2048,2048)
      case 262144:   irope = i; break;   // rope (2048,64,2)
      case 12582912: iW = i;    break;   // W_attn (6144,2048)
      case 20480:    iE = i;    break;   // adapter_emb (10,2048)
      case 16:       iG = i;    break;   // gating (1,16,1,1)
      case 4194304:  iP = i;    break;   // mask (idx 2) then W_proj (idx 4): last wins
      default: break;
    }
  }
  const float* x      = (const float*)d_in[ix];
  const float* rope   = (const float*)d_in[irope];
  const float* W_attn = (const float*)d_in[iW];
  const float* W_proj = (const float*)d_in[iP];
  const float* emb    = (const float*)d_in[iE];
  const float* gating = (const float*)d_in[iG];

  // Workspace layout (fast path, 96 MiB):
  //   [0,48M)   qkv bf16
  //   [48,64M)  xb  = bf16(x)        (4096 x 2048)
  //   [64,88M)  Wab = bf16(W_attn)   (6144 x 2048)
  //   [88,96M)  Wpb = bf16(W_proj)   (2048 x 2048)
  // d_out (32 MiB, dead until proj GEMM) hosts ak/av fp32 (160 KiB) + vt (16 MiB).
  u16*   qkv = (u16*)d_ws;
  float* akb = (float*)d_out;
  float* avb = akb + (size_t)H_ * AL_ * HS_;
  u16*   vtb = (u16*)(avb + (size_t)H_ * AL_ * HS_);

  const bool fast = ws_size >= (size_t)100663296;  // 96 MiB
  if (fast) {
    u16* xb  = qkv + (size_t)25165824;   // 48 MiB / 2
    u16* Wab = xb  + (size_t)8388608;
    u16* Wpb = Wab + (size_t)12582912;
    f32_to_bf16<<<dim3(4096), 256, 0, stream>>>(x, xb, 1048576);
    f32_to_bf16<<<dim3(6144), 256, 0, stream>>>(W_attn, Wab, 1572864);
    f32_to_bf16<<<dim3(2048), 256, 0, stream>>>(W_proj, Wpb, 524288);
    // qkv = xb @ Wab^T   (M=4096, N=6144, K=2048), bf16 out
    gemm_lds<false><<<dim3(48, 32), 256, 0, stream>>>(xb, Wab, qkv, 6144, 2048, 2048);
    adapter_pqkv<<<dim3(1024), 256, 0, stream>>>(emb, W_attn, akb, avb);
    rope_inplace<<<dim3(16384), 256, 0, stream>>>(qkv, rope);
    transpose_v<<<dim3(32, 16, 2), 256, 0, stream>>>(qkv, vtb);
    attn_flash<<<dim3(16, 16, 2), 256, 0, stream>>>(qkv, vtb, akb, avb, gating);
    // out = y @ Wpb^T   (A = y bf16 strided in qkv, lda=6144), FP32 out
    gemm_lds<true><<<dim3(16, 32), 256, 0, stream>>>(qkv, Wpb, (float*)d_out, 2048, 2048, 6144);
  } else {
    gemm_nt<true, true, false><<<dim3(48, 32), 256, 0, stream>>>(
        x, W_attn, qkv, 6144, 2048, 2048);
    adapter_pqkv<<<dim3(1024), 256, 0, stream>>>(emb, W_attn, akb, avb);
    rope_inplace<<<dim3(16384), 256, 0, stream>>>(qkv, rope);
    transpose_v<<<dim3(32, 16, 2), 256, 0, stream>>>(qkv, vtb);
    attn_flash<<<dim3(16, 16, 2), 256, 0, stream>>>(qkv, vtb, akb, avb, gating);
    gemm_nt<false, true, true><<<dim3(16, 32), 256, 0, stream>>>(
        qkv, W_proj, (float*)d_out, 2048, 2048, 6144);
  }
}